// Round 1
// 187.360 us; speedup vs baseline: 1.0458x; 1.0458x over previous
//
#include <hip/hip_runtime.h>
#include <hip/hip_bf16.h>

// ---------------------------------------------------------------------------
// GCN 3-layer, N=50000, E=800000, D=64, fp32 in/out.
// R14: aggemm restructured for gather concurrency. The fused agg+gemm kernel
// previously ran 64 nodes/block (782 blocks = 3128 waves ~= 3.05 waves/SIMD)
// while the pure-agg floor (28us/layer, R9-R12) was measured at 1563 blocks
// (saturating ~4 waves/SIMD at VGPR<=128). The gather is latency-bound, so
// resident waves = throughput. Now: 32 nodes/block, 1564 blocks, Phase A is
// the exact R12 floor form (8 lanes/node, uint4 full-row), launch_bounds
// (256,4) pins VGPR<=128 for 4 blocks/CU. Phase B = 32-row MFMA tile:
// 4 waves = 2 row-subtiles x 2 col-halves, 2 MFMA pairs each.
// Numerics bit-identical to R13 (same neighbor order, same bf16 packing).
// Rest unchanged: agg inner loop = R8/R12 floor form, bucket adjacency
// CAP=64 + XCD-partitioned fill (R3/R4), bf16 table (R6), MFMA gemm (R8).
// ---------------------------------------------------------------------------

#define CAP 64
#define EDGE_CHUNK 1024

typedef __attribute__((ext_vector_type(8))) short bf16x8;
typedef __attribute__((ext_vector_type(4))) float f32x4;

// --- pack two fp32 -> bf16x2 (RNE) ----------------------------------------
__device__ inline unsigned pack_bf16(float a, float b) {
    union { float f; unsigned i; } ua, ub;
    ua.f = a; ub.f = b;
    unsigned x = (ua.i + 0x7fffu + ((ua.i >> 16) & 1u)) >> 16;
    unsigned y = (ub.i + 0x7fffu + ((ub.i >> 16) & 1u)) >> 16;
    return x | (y << 16);
}
__device__ inline unsigned short to_bf16(float a) {
    union { float f; unsigned i; } u; u.f = a;
    return (unsigned short)((u.i + 0x7fffu + ((u.i >> 16) & 1u)) >> 16);
}
// --- accumulate bf16x2 (packed uint) into two floats ----------------------
__device__ inline void acc_bf16x2(unsigned u, float& a, float& b) {
    union { unsigned i; float f; } lo, hi;
    lo.i = u << 16;
    hi.i = u & 0xffff0000u;
    a += lo.f; b += hi.f;
}

// --- fused count+place: slot = atomicAdd(cnt), XCD-partitioned by dst -----
__global__ void fill_kernel(const int* __restrict__ src, const int* __restrict__ dst,
                            int* __restrict__ cnt, int* __restrict__ adj,
                            int E, int npc) {
    int cls = blockIdx.x & 7;          // -> XCD (round-robin heuristic)
    int base = (blockIdx.x >> 3) * EDGE_CHUNK;
    int end = min(base + EDGE_CHUNK, E);
    int lo = cls * npc, hi = lo + npc;
    for (int e = base + threadIdx.x; e < end; e += blockDim.x) {
        int d = dst[e];
        if (d >= lo && d < hi) {
            int p = atomicAdd(&cnt[d], 1);
            adj[(size_t)d * CAP + p] = src[e];
        }
    }
}

// --- stage W (fp32 64x64) into B-fragment order (bf16) in LDS -------------
__device__ inline void stage_W(const float* __restrict__ W, unsigned short* Wb, int t) {
#pragma unroll
    for (int e0 = 0; e0 < 2; e0++) {
        int e = t + e0 * 256;          // frag index 0..511
        int sc = e >> 6;               // s*4 + c
        int l  = e & 63;               // target lane
        int s = sc >> 2, c = sc & 3;
        int nn = c * 16 + (l & 15);
        int kb = s * 32 + (l >> 4) * 8;
        const float* wp = &W[(size_t)kb * 64 + nn];
        unsigned q0 = pack_bf16(wp[0 * 64], wp[1 * 64]);
        unsigned q1 = pack_bf16(wp[2 * 64], wp[3 * 64]);
        unsigned q2 = pack_bf16(wp[4 * 64], wp[5 * 64]);
        unsigned q3 = pack_bf16(wp[6 * 64], wp[7 * 64]);
        *(uint4*)&Wb[e * 8] = make_uint4(q0, q1, q2, q3);
    }
}

// --- g(bf16) = dinv ⊙ (in @ W) via MFMA; 64 rows/block (layer 1 only) -----
__global__ __launch_bounds__(256) void gemm_kernel(const float* __restrict__ in,
                                                   const float* __restrict__ W,
                                                   const int* __restrict__ cnt,
                                                   unsigned short* __restrict__ g, int n) {
    __shared__ unsigned short Wb[512 * 8];
    int t = threadIdx.x;
    stage_W(W, Wb, t);

    int wv = t >> 6;
    int lane = t & 63;
    int quad = lane >> 4;
    int m16 = lane & 15;

    int rowA = blockIdx.x * 64 + wv * 16 + m16;
    union { bf16x8 v; uint4 u; } a0, a1;
    {
        float4 f0 = make_float4(0, 0, 0, 0), f1 = f0, f2 = f0, f3 = f0;
        if (rowA < n) {
            const float* rp = &in[(size_t)rowA * 64];
            f0 = *(const float4*)&rp[quad * 8];
            f1 = *(const float4*)&rp[quad * 8 + 4];
            f2 = *(const float4*)&rp[32 + quad * 8];
            f3 = *(const float4*)&rp[32 + quad * 8 + 4];
        }
        a0.u = make_uint4(pack_bf16(f0.x, f0.y), pack_bf16(f0.z, f0.w),
                          pack_bf16(f1.x, f1.y), pack_bf16(f1.z, f1.w));
        a1.u = make_uint4(pack_bf16(f2.x, f2.y), pack_bf16(f2.z, f2.w),
                          pack_bf16(f3.x, f3.y), pack_bf16(f3.z, f3.w));
    }
    __syncthreads();

    f32x4 acc[4];
#pragma unroll
    for (int c = 0; c < 4; c++) {
        bf16x8 b0 = *(const bf16x8*)&Wb[((size_t)(0 * 4 + c) * 64 + lane) * 8];
        bf16x8 b1 = *(const bf16x8*)&Wb[((size_t)(1 * 4 + c) * 64 + lane) * 8];
        f32x4 z = {0.f, 0.f, 0.f, 0.f};
        z = __builtin_amdgcn_mfma_f32_16x16x32_bf16(a0.v, b0, z, 0, 0, 0);
        z = __builtin_amdgcn_mfma_f32_16x16x32_bf16(a1.v, b1, z, 0, 0, 0);
        acc[c] = z;
    }

    int rowbase = blockIdx.x * 64 + wv * 16 + quad * 4;
    float dv[4];
#pragma unroll
    for (int r = 0; r < 4; r++) {
        int row = rowbase + r;
        dv[r] = (row < n) ? rsqrtf((float)(cnt[row] + 1)) : 0.f;
    }
#pragma unroll
    for (int c = 0; c < 4; c++) {
#pragma unroll
        for (int r = 0; r < 4; r++) {
            int row = rowbase + r;
            if (row < n)
                g[(size_t)row * 64 + c * 16 + m16] = to_bf16(acc[c][r] * dv[r]);
        }
    }
}

// --- fused agg(l) + gemm(l+1); 32 nodes/block (R14) -----------------------
// Phase A: R12 floor form — 8 lanes/node, uint4 (16B) full-row gather, 32
// nodes in one pass. Epilogue h = relu(dinv*sum + bias) + res; optional h
// write; deposit h (bf16) into A-frag LDS slot ((s*8+chunk)*16+m)*8 where
// s=row>>4, m=row&15, chunk=lane&7 (8 feats/lane = exactly one K-chunk).
// Phase B: 4 waves = 2 row-subtiles x 2 col-halves; 2 MFMA pairs per wave;
// g_out = dinv ⊙ (h@W). launch_bounds(256,4): VGPR<=128 -> 4 blocks/CU.
template <int WRITE_H>
__global__ __launch_bounds__(256, 4) void aggemm_kernel(
        const unsigned short* __restrict__ g_in,
        const int* __restrict__ cnt,
        const int* __restrict__ adj,
        const float* __restrict__ bias,
        const float* __restrict__ res,
        const float* __restrict__ W,
        float* __restrict__ h_out,
        unsigned short* __restrict__ g_out,
        int n) {
    __shared__ unsigned short Wb[512 * 8];     // 8 KB B-frags
    __shared__ unsigned short Afrag[256 * 8];  // 4 KB A-frags (32 rows)
    int t = threadIdx.x;
    stage_W(W, Wb, t);

    // ---- Phase A: aggregate 32 nodes, 8 lanes/node, uint4 ----
    int r  = t >> 3;                   // node-in-block 0..31
    int lg = t & 7;
    const int c8 = lg * 8;
    int i = blockIdx.x * 32 + r;
    float v0 = 0.f, v1 = 0.f, v2 = 0.f, v3 = 0.f;
    float v4 = 0.f, v5 = 0.f, v6 = 0.f, v7 = 0.f;
    if (i < n) {
        int deg = cnt[i];
        const int* lst = adj + (size_t)i * CAP;
        float4 rr0 = *(const float4*)&res[(size_t)i * 64 + c8];      // hoisted
        float4 rr1 = *(const float4*)&res[(size_t)i * 64 + c8 + 4];
        float a0 = 0.f, a1 = 0.f, a2 = 0.f, a3 = 0.f;
        float a4 = 0.f, a5 = 0.f, a6 = 0.f, a7 = 0.f;
        {   // self loop
            uint4 v = *(const uint4*)&g_in[(size_t)i * 64 + c8];
            acc_bf16x2(v.x, a0, a1); acc_bf16x2(v.y, a2, a3);
            acc_bf16x2(v.z, a4, a5); acc_bf16x2(v.w, a6, a7);
        }
        int k = 0;
        for (; k + 8 <= deg; k += 8) {
            int4 ja = *(const int4*)&lst[k];
            int4 jb = *(const int4*)&lst[k + 4];
            uint4 w0 = *(const uint4*)&g_in[(size_t)ja.x * 64 + c8];
            uint4 w1 = *(const uint4*)&g_in[(size_t)ja.y * 64 + c8];
            uint4 w2 = *(const uint4*)&g_in[(size_t)ja.z * 64 + c8];
            uint4 w3 = *(const uint4*)&g_in[(size_t)ja.w * 64 + c8];
            uint4 w4 = *(const uint4*)&g_in[(size_t)jb.x * 64 + c8];
            uint4 w5 = *(const uint4*)&g_in[(size_t)jb.y * 64 + c8];
            uint4 w6 = *(const uint4*)&g_in[(size_t)jb.z * 64 + c8];
            uint4 w7 = *(const uint4*)&g_in[(size_t)jb.w * 64 + c8];
            acc_bf16x2(w0.x, a0, a1); acc_bf16x2(w0.y, a2, a3);
            acc_bf16x2(w0.z, a4, a5); acc_bf16x2(w0.w, a6, a7);
            acc_bf16x2(w1.x, a0, a1); acc_bf16x2(w1.y, a2, a3);
            acc_bf16x2(w1.z, a4, a5); acc_bf16x2(w1.w, a6, a7);
            acc_bf16x2(w2.x, a0, a1); acc_bf16x2(w2.y, a2, a3);
            acc_bf16x2(w2.z, a4, a5); acc_bf16x2(w2.w, a6, a7);
            acc_bf16x2(w3.x, a0, a1); acc_bf16x2(w3.y, a2, a3);
            acc_bf16x2(w3.z, a4, a5); acc_bf16x2(w3.w, a6, a7);
            acc_bf16x2(w4.x, a0, a1); acc_bf16x2(w4.y, a2, a3);
            acc_bf16x2(w4.z, a4, a5); acc_bf16x2(w4.w, a6, a7);
            acc_bf16x2(w5.x, a0, a1); acc_bf16x2(w5.y, a2, a3);
            acc_bf16x2(w5.z, a4, a5); acc_bf16x2(w5.w, a6, a7);
            acc_bf16x2(w6.x, a0, a1); acc_bf16x2(w6.y, a2, a3);
            acc_bf16x2(w6.z, a4, a5); acc_bf16x2(w6.w, a6, a7);
            acc_bf16x2(w7.x, a0, a1); acc_bf16x2(w7.y, a2, a3);
            acc_bf16x2(w7.z, a4, a5); acc_bf16x2(w7.w, a6, a7);
        }
        if (k + 4 <= deg) {
            int4 ja = *(const int4*)&lst[k];
            uint4 w0 = *(const uint4*)&g_in[(size_t)ja.x * 64 + c8];
            uint4 w1 = *(const uint4*)&g_in[(size_t)ja.y * 64 + c8];
            uint4 w2 = *(const uint4*)&g_in[(size_t)ja.z * 64 + c8];
            uint4 w3 = *(const uint4*)&g_in[(size_t)ja.w * 64 + c8];
            acc_bf16x2(w0.x, a0, a1); acc_bf16x2(w0.y, a2, a3);
            acc_bf16x2(w0.z, a4, a5); acc_bf16x2(w0.w, a6, a7);
            acc_bf16x2(w1.x, a0, a1); acc_bf16x2(w1.y, a2, a3);
            acc_bf16x2(w1.z, a4, a5); acc_bf16x2(w1.w, a6, a7);
            acc_bf16x2(w2.x, a0, a1); acc_bf16x2(w2.y, a2, a3);
            acc_bf16x2(w2.z, a4, a5); acc_bf16x2(w2.w, a6, a7);
            acc_bf16x2(w3.x, a0, a1); acc_bf16x2(w3.y, a2, a3);
            acc_bf16x2(w3.z, a4, a5); acc_bf16x2(w3.w, a6, a7);
            k += 4;
        }
        for (; k < deg; k++) {
            uint4 v = *(const uint4*)&g_in[(size_t)lst[k] * 64 + c8];
            acc_bf16x2(v.x, a0, a1); acc_bf16x2(v.y, a2, a3);
            acc_bf16x2(v.z, a4, a5); acc_bf16x2(v.w, a6, a7);
        }
        float dvv = rsqrtf((float)(deg + 1));
        float4 b0 = *(const float4*)&bias[c8];
        float4 b1 = *(const float4*)&bias[c8 + 4];
        v0 = fmaxf(dvv * a0 + b0.x, 0.f) + rr0.x;
        v1 = fmaxf(dvv * a1 + b0.y, 0.f) + rr0.y;
        v2 = fmaxf(dvv * a2 + b0.z, 0.f) + rr0.z;
        v3 = fmaxf(dvv * a3 + b0.w, 0.f) + rr0.w;
        v4 = fmaxf(dvv * a4 + b1.x, 0.f) + rr1.x;
        v5 = fmaxf(dvv * a5 + b1.y, 0.f) + rr1.y;
        v6 = fmaxf(dvv * a6 + b1.z, 0.f) + rr1.z;
        v7 = fmaxf(dvv * a7 + b1.w, 0.f) + rr1.w;
        if (WRITE_H) {
            *(float4*)&h_out[(size_t)i * 64 + c8]     = make_float4(v0, v1, v2, v3);
            *(float4*)&h_out[(size_t)i * 64 + c8 + 4] = make_float4(v4, v5, v6, v7);
        }
    }
    // deposit into A-frag LDS (zeros for i>=n); one ds_write_b128 per lane
    {
        uint4 pk;
        pk.x = pack_bf16(v0, v1);
        pk.y = pack_bf16(v2, v3);
        pk.z = pack_bf16(v4, v5);
        pk.w = pack_bf16(v6, v7);
        int sA = r >> 4, mA = r & 15;
        *(uint4*)&Afrag[((size_t)(sA * 8 + lg) * 16 + mA) * 8] = pk;
    }
    __syncthreads();

    // ---- Phase B: MFMA gemm on the 32-row tile ----
    int wv = t >> 6;
    int lane = t & 63;
    int quad = lane >> 4;
    int m16 = lane & 15;
    int sB = wv & 1;                   // row sub-tile 0..1
    int ch = wv >> 1;                  // col half 0..1
    bf16x8 af0 = *(const bf16x8*)&Afrag[((size_t)(sB * 8 + quad) * 16 + m16) * 8];
    bf16x8 af1 = *(const bf16x8*)&Afrag[((size_t)(sB * 8 + 4 + quad) * 16 + m16) * 8];
    f32x4 acc[2];
#pragma unroll
    for (int c2 = 0; c2 < 2; c2++) {
        int c = ch * 2 + c2;
        bf16x8 b0 = *(const bf16x8*)&Wb[((size_t)(0 * 4 + c) * 64 + lane) * 8];
        bf16x8 b1 = *(const bf16x8*)&Wb[((size_t)(1 * 4 + c) * 64 + lane) * 8];
        f32x4 z = {0.f, 0.f, 0.f, 0.f};
        z = __builtin_amdgcn_mfma_f32_16x16x32_bf16(af0, b0, z, 0, 0, 0);
        z = __builtin_amdgcn_mfma_f32_16x16x32_bf16(af1, b1, z, 0, 0, 0);
        acc[c2] = z;
    }
    int rowbase = blockIdx.x * 32 + sB * 16 + quad * 4;
    float dv2[4];
#pragma unroll
    for (int rr = 0; rr < 4; rr++) {
        int row = rowbase + rr;
        dv2[rr] = (row < n) ? rsqrtf((float)(cnt[row] + 1)) : 0.f;
    }
#pragma unroll
    for (int c2 = 0; c2 < 2; c2++) {
        int c = ch * 2 + c2;
#pragma unroll
        for (int rr = 0; rr < 4; rr++) {
            int row = rowbase + rr;
            if (row < n)
                g_out[(size_t)row * 64 + c * 16 + m16] = to_bf16(acc[c2][rr] * dv2[rr]);
        }
    }
}

// --- final aggregation (R12 form): 8 lanes/node uint4, int4 indices -------
__global__ __launch_bounds__(256) void agg_kernel(const unsigned short* __restrict__ g,
                                                  const int* __restrict__ cnt,
                                                  const int* __restrict__ adj,
                                                  const float* __restrict__ bias,
                                                  float* __restrict__ out, int n) {
    int t = threadIdx.x;
    int lg = t & 7;
    int i = blockIdx.x * 32 + (t >> 3);
    if (i >= n) return;
    int deg = cnt[i];
    const int* lst = adj + (size_t)i * CAP;
    const int c8 = lg * 8;
    size_t rowoff = (size_t)i * 64 + c8;
    float a0 = 0.f, a1 = 0.f, a2 = 0.f, a3 = 0.f;
    float a4 = 0.f, a5 = 0.f, a6 = 0.f, a7 = 0.f;
    {   // self loop
        uint4 v = *(const uint4*)&g[(size_t)i * 64 + c8];
        acc_bf16x2(v.x, a0, a1); acc_bf16x2(v.y, a2, a3);
        acc_bf16x2(v.z, a4, a5); acc_bf16x2(v.w, a6, a7);
    }
    int k = 0;
    for (; k + 8 <= deg; k += 8) {
        int4 ja = *(const int4*)&lst[k];
        int4 jb = *(const int4*)&lst[k + 4];
        uint4 v0 = *(const uint4*)&g[(size_t)ja.x * 64 + c8];
        uint4 v1 = *(const uint4*)&g[(size_t)ja.y * 64 + c8];
        uint4 v2 = *(const uint4*)&g[(size_t)ja.z * 64 + c8];
        uint4 v3 = *(const uint4*)&g[(size_t)ja.w * 64 + c8];
        uint4 v4 = *(const uint4*)&g[(size_t)jb.x * 64 + c8];
        uint4 v5 = *(const uint4*)&g[(size_t)jb.y * 64 + c8];
        uint4 v6 = *(const uint4*)&g[(size_t)jb.z * 64 + c8];
        uint4 v7 = *(const uint4*)&g[(size_t)jb.w * 64 + c8];
        acc_bf16x2(v0.x, a0, a1); acc_bf16x2(v0.y, a2, a3);
        acc_bf16x2(v0.z, a4, a5); acc_bf16x2(v0.w, a6, a7);
        acc_bf16x2(v1.x, a0, a1); acc_bf16x2(v1.y, a2, a3);
        acc_bf16x2(v1.z, a4, a5); acc_bf16x2(v1.w, a6, a7);
        acc_bf16x2(v2.x, a0, a1); acc_bf16x2(v2.y, a2, a3);
        acc_bf16x2(v2.z, a4, a5); acc_bf16x2(v2.w, a6, a7);
        acc_bf16x2(v3.x, a0, a1); acc_bf16x2(v3.y, a2, a3);
        acc_bf16x2(v3.z, a4, a5); acc_bf16x2(v3.w, a6, a7);
        acc_bf16x2(v4.x, a0, a1); acc_bf16x2(v4.y, a2, a3);
        acc_bf16x2(v4.z, a4, a5); acc_bf16x2(v4.w, a6, a7);
        acc_bf16x2(v5.x, a0, a1); acc_bf16x2(v5.y, a2, a3);
        acc_bf16x2(v5.z, a4, a5); acc_bf16x2(v5.w, a6, a7);
        acc_bf16x2(v6.x, a0, a1); acc_bf16x2(v6.y, a2, a3);
        acc_bf16x2(v6.z, a4, a5); acc_bf16x2(v6.w, a6, a7);
        acc_bf16x2(v7.x, a0, a1); acc_bf16x2(v7.y, a2, a3);
        acc_bf16x2(v7.z, a4, a5); acc_bf16x2(v7.w, a6, a7);
    }
    if (k + 4 <= deg) {
        int4 ja = *(const int4*)&lst[k];
        uint4 v0 = *(const uint4*)&g[(size_t)ja.x * 64 + c8];
        uint4 v1 = *(const uint4*)&g[(size_t)ja.y * 64 + c8];
        uint4 v2 = *(const uint4*)&g[(size_t)ja.z * 64 + c8];
        uint4 v3 = *(const uint4*)&g[(size_t)ja.w * 64 + c8];
        acc_bf16x2(v0.x, a0, a1); acc_bf16x2(v0.y, a2, a3);
        acc_bf16x2(v0.z, a4, a5); acc_bf16x2(v0.w, a6, a7);
        acc_bf16x2(v1.x, a0, a1); acc_bf16x2(v1.y, a2, a3);
        acc_bf16x2(v1.z, a4, a5); acc_bf16x2(v1.w, a6, a7);
        acc_bf16x2(v2.x, a0, a1); acc_bf16x2(v2.y, a2, a3);
        acc_bf16x2(v2.z, a4, a5); acc_bf16x2(v2.w, a6, a7);
        acc_bf16x2(v3.x, a0, a1); acc_bf16x2(v3.y, a2, a3);
        acc_bf16x2(v3.z, a4, a5); acc_bf16x2(v3.w, a6, a7);
        k += 4;
    }
    for (; k < deg; k++) {
        uint4 v = *(const uint4*)&g[(size_t)lst[k] * 64 + c8];
        acc_bf16x2(v.x, a0, a1); acc_bf16x2(v.y, a2, a3);
        acc_bf16x2(v.z, a4, a5); acc_bf16x2(v.w, a6, a7);
    }
    float dv = rsqrtf((float)(deg + 1));
    float4 b0 = *(const float4*)&bias[c8];
    float4 b1 = *(const float4*)&bias[c8 + 4];
    float4 o0, o1;
    o0.x = dv * a0 + b0.x; o0.y = dv * a1 + b0.y;
    o0.z = dv * a2 + b0.z; o0.w = dv * a3 + b0.w;
    o1.x = dv * a4 + b1.x; o1.y = dv * a5 + b1.y;
    o1.z = dv * a6 + b1.z; o1.w = dv * a7 + b1.w;
    *(float4*)&out[rowoff] = o0;
    *(float4*)&out[rowoff + 4] = o1;
}

extern "C" void kernel_launch(void* const* d_in, const int* in_sizes, int n_in,
                              void* d_out, int out_size, void* d_ws, size_t ws_size,
                              hipStream_t stream) {
    const float* x  = (const float*)d_in[0];
    const int*   ei = (const int*)d_in[1];
    const float* W1 = (const float*)d_in[2];
    const float* b1 = (const float*)d_in[3];
    const float* W2 = (const float*)d_in[4];
    const float* b2 = (const float*)d_in[5];
    const float* W3 = (const float*)d_in[6];
    const float* b3 = (const float*)d_in[7];
    float* out = (float*)d_out;

    const int N = in_sizes[0] / 64;
    const int E = in_sizes[1] / 2;
    const int* src = ei;
    const int* dst = ei + E;
    const int npc = (N + 7) / 8;
    const int nEdgeChunks = (E + EDGE_CHUNK - 1) / EDGE_CHUNK;

    // workspace layout
    char* p = (char*)d_ws;
    int*            cnt = (int*)p;            p += ((N + 63) / 64) * 64 * 4;
    int*            adj = (int*)p;            p += ((size_t)N + 1) * CAP * 4;
    unsigned short* ga  = (unsigned short*)p; p += (size_t)N * 64 * 2;
    unsigned short* gb  = (unsigned short*)p; p += (size_t)N * 64 * 2;
    float*          h1  = (float*)p;          p += (size_t)N * 64 * 4;

    const int tileBlocks = (N + 63) / 64;   // gemm (64-row MFMA tiles)
    const int halfBlocks = (N + 31) / 32;   // aggemm + final agg (32 nodes)

    // --- bucket adjacency build (ws re-poisoned every call) ---
    hipMemsetAsync(cnt, 0, (size_t)N * 4, stream);
    fill_kernel<<<nEdgeChunks * 8, 256, 0, stream>>>(src, dst, cnt, adj, E, npc);

    // --- layer 1 gemm: ga = dinv ⊙ (x@W1) ---
    gemm_kernel<<<tileBlocks, 256, 0, stream>>>(x, W1, cnt, ga, N);
    // --- fused: h1 = relu(agg(ga))+x ; gb = dinv ⊙ (h1@W2) ---
    aggemm_kernel<1><<<halfBlocks, 256, 0, stream>>>(ga, cnt, adj, b1, x, W2, h1, gb, N);
    // --- fused: h2 = relu(agg(gb))+h1 (kept in-kernel) ; ga = dinv ⊙ (h2@W3) ---
    aggemm_kernel<0><<<halfBlocks, 256, 0, stream>>>(gb, cnt, adj, b2, h1, W3, nullptr, ga, N);
    // --- final: out = agg(ga) + b3 ---
    agg_kernel<<<halfBlocks, 256, 0, stream>>>(ga, cnt, adj, b3, out, N);
}

// Round 2
// 182.433 us; speedup vs baseline: 1.0740x; 1.0270x over previous
//
#include <hip/hip_runtime.h>
#include <hip/hip_bf16.h>

// ---------------------------------------------------------------------------
// GCN 3-layer, N=50000, E=800000, D=64, fp32 in/out.
// R15: software-pipelined gathers. Each 8-row gather batch previously paid
// two serialized memory latencies (index int4 pair -> row gathers). Now the
// index pair for batch b+1 is loaded while batch b's rows are in flight, so
// row gathers issue immediately at each loop head. Applied to all three
// gather loops (aggemm x2, final agg). Numerics bit-identical (same per-node
// accumulation order). Also: stage_W moved after Phase A (its 8 VMEM loads
// no longer compete with the gather queue at block start; latency hides
// before __syncthreads); Phase A deposits dinv into LDS for Phase B (kills
// the cnt re-load + rsqrt); explicit launch_bounds(256,4) on agg_kernel.
// R14: 32 nodes/block aggemm (1564 blocks, 4 blocks/CU) for gather
// concurrency. R13: agg(l)+gemm(l+1) fusion through LDS A-frags. R8/R12
// gather floor form, bucket adjacency CAP=64 + XCD-partitioned fill (R3/R4),
// bf16 table (R6), MFMA gemm (R8).
// ---------------------------------------------------------------------------

#define CAP 64
#define EDGE_CHUNK 1024

typedef __attribute__((ext_vector_type(8))) short bf16x8;
typedef __attribute__((ext_vector_type(4))) float f32x4;

// --- pack two fp32 -> bf16x2 (RNE) ----------------------------------------
__device__ inline unsigned pack_bf16(float a, float b) {
    union { float f; unsigned i; } ua, ub;
    ua.f = a; ub.f = b;
    unsigned x = (ua.i + 0x7fffu + ((ua.i >> 16) & 1u)) >> 16;
    unsigned y = (ub.i + 0x7fffu + ((ub.i >> 16) & 1u)) >> 16;
    return x | (y << 16);
}
__device__ inline unsigned short to_bf16(float a) {
    union { float f; unsigned i; } u; u.f = a;
    return (unsigned short)((u.i + 0x7fffu + ((u.i >> 16) & 1u)) >> 16);
}
// --- accumulate bf16x2 (packed uint) into two floats ----------------------
__device__ inline void acc_bf16x2(unsigned u, float& a, float& b) {
    union { unsigned i; float f; } lo, hi;
    lo.i = u << 16;
    hi.i = u & 0xffff0000u;
    a += lo.f; b += hi.f;
}

// --- fused count+place: slot = atomicAdd(cnt), XCD-partitioned by dst -----
__global__ void fill_kernel(const int* __restrict__ src, const int* __restrict__ dst,
                            int* __restrict__ cnt, int* __restrict__ adj,
                            int E, int npc) {
    int cls = blockIdx.x & 7;          // -> XCD (round-robin heuristic)
    int base = (blockIdx.x >> 3) * EDGE_CHUNK;
    int end = min(base + EDGE_CHUNK, E);
    int lo = cls * npc, hi = lo + npc;
    for (int e = base + threadIdx.x; e < end; e += blockDim.x) {
        int d = dst[e];
        if (d >= lo && d < hi) {
            int p = atomicAdd(&cnt[d], 1);
            adj[(size_t)d * CAP + p] = src[e];
        }
    }
}

// --- stage W (fp32 64x64) into B-fragment order (bf16) in LDS -------------
__device__ inline void stage_W(const float* __restrict__ W, unsigned short* Wb, int t) {
#pragma unroll
    for (int e0 = 0; e0 < 2; e0++) {
        int e = t + e0 * 256;          // frag index 0..511
        int sc = e >> 6;               // s*4 + c
        int l  = e & 63;               // target lane
        int s = sc >> 2, c = sc & 3;
        int nn = c * 16 + (l & 15);
        int kb = s * 32 + (l >> 4) * 8;
        const float* wp = &W[(size_t)kb * 64 + nn];
        unsigned q0 = pack_bf16(wp[0 * 64], wp[1 * 64]);
        unsigned q1 = pack_bf16(wp[2 * 64], wp[3 * 64]);
        unsigned q2 = pack_bf16(wp[4 * 64], wp[5 * 64]);
        unsigned q3 = pack_bf16(wp[6 * 64], wp[7 * 64]);
        *(uint4*)&Wb[e * 8] = make_uint4(q0, q1, q2, q3);
    }
}

// --- g(bf16) = dinv ⊙ (in @ W) via MFMA; 64 rows/block (layer 1 only) -----
__global__ __launch_bounds__(256) void gemm_kernel(const float* __restrict__ in,
                                                   const float* __restrict__ W,
                                                   const int* __restrict__ cnt,
                                                   unsigned short* __restrict__ g, int n) {
    __shared__ unsigned short Wb[512 * 8];
    int t = threadIdx.x;
    stage_W(W, Wb, t);

    int wv = t >> 6;
    int lane = t & 63;
    int quad = lane >> 4;
    int m16 = lane & 15;

    int rowA = blockIdx.x * 64 + wv * 16 + m16;
    union { bf16x8 v; uint4 u; } a0, a1;
    {
        float4 f0 = make_float4(0, 0, 0, 0), f1 = f0, f2 = f0, f3 = f0;
        if (rowA < n) {
            const float* rp = &in[(size_t)rowA * 64];
            f0 = *(const float4*)&rp[quad * 8];
            f1 = *(const float4*)&rp[quad * 8 + 4];
            f2 = *(const float4*)&rp[32 + quad * 8];
            f3 = *(const float4*)&rp[32 + quad * 8 + 4];
        }
        a0.u = make_uint4(pack_bf16(f0.x, f0.y), pack_bf16(f0.z, f0.w),
                          pack_bf16(f1.x, f1.y), pack_bf16(f1.z, f1.w));
        a1.u = make_uint4(pack_bf16(f2.x, f2.y), pack_bf16(f2.z, f2.w),
                          pack_bf16(f3.x, f3.y), pack_bf16(f3.z, f3.w));
    }
    __syncthreads();

    f32x4 acc[4];
#pragma unroll
    for (int c = 0; c < 4; c++) {
        bf16x8 b0 = *(const bf16x8*)&Wb[((size_t)(0 * 4 + c) * 64 + lane) * 8];
        bf16x8 b1 = *(const bf16x8*)&Wb[((size_t)(1 * 4 + c) * 64 + lane) * 8];
        f32x4 z = {0.f, 0.f, 0.f, 0.f};
        z = __builtin_amdgcn_mfma_f32_16x16x32_bf16(a0.v, b0, z, 0, 0, 0);
        z = __builtin_amdgcn_mfma_f32_16x16x32_bf16(a1.v, b1, z, 0, 0, 0);
        acc[c] = z;
    }

    int rowbase = blockIdx.x * 64 + wv * 16 + quad * 4;
    float dv[4];
#pragma unroll
    for (int r = 0; r < 4; r++) {
        int row = rowbase + r;
        dv[r] = (row < n) ? rsqrtf((float)(cnt[row] + 1)) : 0.f;
    }
#pragma unroll
    for (int c = 0; c < 4; c++) {
#pragma unroll
        for (int r = 0; r < 4; r++) {
            int row = rowbase + r;
            if (row < n)
                g[(size_t)row * 64 + c * 16 + m16] = to_bf16(acc[c][r] * dv[r]);
        }
    }
}

// --- fused agg(l) + gemm(l+1); 32 nodes/block (R14/R15) -------------------
// Phase A: R12 floor form — 8 lanes/node, uint4 (16B) full-row gather, with
// one-batch-ahead index prefetch (R15). Epilogue h = relu(dinv*sum+bias)+res;
// optional h write; deposit h (bf16) into A-frag LDS. Phase B: 4 waves =
// 2 row-subtiles x 2 col-halves; 2 MFMA pairs per wave; g_out = dinv ⊙ (h@W)
// with dinv pulled from LDS (deposited by Phase A).
template <int WRITE_H>
__global__ __launch_bounds__(256, 4) void aggemm_kernel(
        const unsigned short* __restrict__ g_in,
        const int* __restrict__ cnt,
        const int* __restrict__ adj,
        const float* __restrict__ bias,
        const float* __restrict__ res,
        const float* __restrict__ W,
        float* __restrict__ h_out,
        unsigned short* __restrict__ g_out,
        int n) {
    __shared__ unsigned short Wb[512 * 8];     // 8 KB B-frags
    __shared__ unsigned short Afrag[256 * 8];  // 4 KB A-frags (32 rows)
    __shared__ float dsh[32];                  // per-node dinv for Phase B
    int t = threadIdx.x;

    // ---- Phase A: aggregate 32 nodes, 8 lanes/node, uint4 ----
    int r  = t >> 3;                   // node-in-block 0..31
    int lg = t & 7;
    const int c8 = lg * 8;
    int i = blockIdx.x * 32 + r;
    float v0 = 0.f, v1 = 0.f, v2 = 0.f, v3 = 0.f;
    float v4 = 0.f, v5 = 0.f, v6 = 0.f, v7 = 0.f;
    float dvv = 0.f;
    if (i < n) {
        int deg = cnt[i];
        const int* lst = adj + (size_t)i * CAP;
        float4 rr0 = *(const float4*)&res[(size_t)i * 64 + c8];      // hoisted
        float4 rr1 = *(const float4*)&res[(size_t)i * 64 + c8 + 4];
        float a0 = 0.f, a1 = 0.f, a2 = 0.f, a3 = 0.f;
        float a4 = 0.f, a5 = 0.f, a6 = 0.f, a7 = 0.f;
        {   // self loop
            uint4 v = *(const uint4*)&g_in[(size_t)i * 64 + c8];
            acc_bf16x2(v.x, a0, a1); acc_bf16x2(v.y, a2, a3);
            acc_bf16x2(v.z, a4, a5); acc_bf16x2(v.w, a6, a7);
        }
        int nfull = deg >> 3;          // full 8-batches
        int4 ja, jb;
        if (nfull > 0) { ja = *(const int4*)&lst[0]; jb = *(const int4*)&lst[4]; }
        for (int b = 0; b < nfull; b++) {
            int4 na = ja, nb = jb;     // prefetch next batch's indices
            if (b + 1 < nfull) {
                na = *(const int4*)&lst[(b + 1) * 8];
                nb = *(const int4*)&lst[(b + 1) * 8 + 4];
            }
            uint4 w0 = *(const uint4*)&g_in[(size_t)ja.x * 64 + c8];
            uint4 w1 = *(const uint4*)&g_in[(size_t)ja.y * 64 + c8];
            uint4 w2 = *(const uint4*)&g_in[(size_t)ja.z * 64 + c8];
            uint4 w3 = *(const uint4*)&g_in[(size_t)ja.w * 64 + c8];
            uint4 w4 = *(const uint4*)&g_in[(size_t)jb.x * 64 + c8];
            uint4 w5 = *(const uint4*)&g_in[(size_t)jb.y * 64 + c8];
            uint4 w6 = *(const uint4*)&g_in[(size_t)jb.z * 64 + c8];
            uint4 w7 = *(const uint4*)&g_in[(size_t)jb.w * 64 + c8];
            acc_bf16x2(w0.x, a0, a1); acc_bf16x2(w0.y, a2, a3);
            acc_bf16x2(w0.z, a4, a5); acc_bf16x2(w0.w, a6, a7);
            acc_bf16x2(w1.x, a0, a1); acc_bf16x2(w1.y, a2, a3);
            acc_bf16x2(w1.z, a4, a5); acc_bf16x2(w1.w, a6, a7);
            acc_bf16x2(w2.x, a0, a1); acc_bf16x2(w2.y, a2, a3);
            acc_bf16x2(w2.z, a4, a5); acc_bf16x2(w2.w, a6, a7);
            acc_bf16x2(w3.x, a0, a1); acc_bf16x2(w3.y, a2, a3);
            acc_bf16x2(w3.z, a4, a5); acc_bf16x2(w3.w, a6, a7);
            acc_bf16x2(w4.x, a0, a1); acc_bf16x2(w4.y, a2, a3);
            acc_bf16x2(w4.z, a4, a5); acc_bf16x2(w4.w, a6, a7);
            acc_bf16x2(w5.x, a0, a1); acc_bf16x2(w5.y, a2, a3);
            acc_bf16x2(w5.z, a4, a5); acc_bf16x2(w5.w, a6, a7);
            acc_bf16x2(w6.x, a0, a1); acc_bf16x2(w6.y, a2, a3);
            acc_bf16x2(w6.z, a4, a5); acc_bf16x2(w6.w, a6, a7);
            acc_bf16x2(w7.x, a0, a1); acc_bf16x2(w7.y, a2, a3);
            acc_bf16x2(w7.z, a4, a5); acc_bf16x2(w7.w, a6, a7);
            ja = na; jb = nb;
        }
        int k = nfull * 8;
        if (k + 4 <= deg) {
            int4 j4 = *(const int4*)&lst[k];
            uint4 w0 = *(const uint4*)&g_in[(size_t)j4.x * 64 + c8];
            uint4 w1 = *(const uint4*)&g_in[(size_t)j4.y * 64 + c8];
            uint4 w2 = *(const uint4*)&g_in[(size_t)j4.z * 64 + c8];
            uint4 w3 = *(const uint4*)&g_in[(size_t)j4.w * 64 + c8];
            acc_bf16x2(w0.x, a0, a1); acc_bf16x2(w0.y, a2, a3);
            acc_bf16x2(w0.z, a4, a5); acc_bf16x2(w0.w, a6, a7);
            acc_bf16x2(w1.x, a0, a1); acc_bf16x2(w1.y, a2, a3);
            acc_bf16x2(w1.z, a4, a5); acc_bf16x2(w1.w, a6, a7);
            acc_bf16x2(w2.x, a0, a1); acc_bf16x2(w2.y, a2, a3);
            acc_bf16x2(w2.z, a4, a5); acc_bf16x2(w2.w, a6, a7);
            acc_bf16x2(w3.x, a0, a1); acc_bf16x2(w3.y, a2, a3);
            acc_bf16x2(w3.z, a4, a5); acc_bf16x2(w3.w, a6, a7);
            k += 4;
        }
        for (; k < deg; k++) {
            uint4 v = *(const uint4*)&g_in[(size_t)lst[k] * 64 + c8];
            acc_bf16x2(v.x, a0, a1); acc_bf16x2(v.y, a2, a3);
            acc_bf16x2(v.z, a4, a5); acc_bf16x2(v.w, a6, a7);
        }
        dvv = rsqrtf((float)(deg + 1));
        float4 b0 = *(const float4*)&bias[c8];
        float4 b1 = *(const float4*)&bias[c8 + 4];
        v0 = fmaxf(dvv * a0 + b0.x, 0.f) + rr0.x;
        v1 = fmaxf(dvv * a1 + b0.y, 0.f) + rr0.y;
        v2 = fmaxf(dvv * a2 + b0.z, 0.f) + rr0.z;
        v3 = fmaxf(dvv * a3 + b0.w, 0.f) + rr0.w;
        v4 = fmaxf(dvv * a4 + b1.x, 0.f) + rr1.x;
        v5 = fmaxf(dvv * a5 + b1.y, 0.f) + rr1.y;
        v6 = fmaxf(dvv * a6 + b1.z, 0.f) + rr1.z;
        v7 = fmaxf(dvv * a7 + b1.w, 0.f) + rr1.w;
        if (WRITE_H) {
            *(float4*)&h_out[(size_t)i * 64 + c8]     = make_float4(v0, v1, v2, v3);
            *(float4*)&h_out[(size_t)i * 64 + c8 + 4] = make_float4(v4, v5, v6, v7);
        }
    }
    // stage W after the gather: its VMEM doesn't compete with the gather
    // queue; latency hides under other waves' Phase A before the barrier.
    stage_W(W, Wb, t);
    // deposit into A-frag LDS (zeros for i>=n); one ds_write_b128 per lane
    {
        uint4 pk;
        pk.x = pack_bf16(v0, v1);
        pk.y = pack_bf16(v2, v3);
        pk.z = pack_bf16(v4, v5);
        pk.w = pack_bf16(v6, v7);
        int sA = r >> 4, mA = r & 15;
        *(uint4*)&Afrag[((size_t)(sA * 8 + lg) * 16 + mA) * 8] = pk;
        if (lg == 0) dsh[r] = dvv;     // dinv for Phase B epilogue
    }
    __syncthreads();

    // ---- Phase B: MFMA gemm on the 32-row tile ----
    int wv = t >> 6;
    int lane = t & 63;
    int quad = lane >> 4;
    int m16 = lane & 15;
    int sB = wv & 1;                   // row sub-tile 0..1
    int ch = wv >> 1;                  // col half 0..1
    bf16x8 af0 = *(const bf16x8*)&Afrag[((size_t)(sB * 8 + quad) * 16 + m16) * 8];
    bf16x8 af1 = *(const bf16x8*)&Afrag[((size_t)(sB * 8 + 4 + quad) * 16 + m16) * 8];
    f32x4 acc[2];
#pragma unroll
    for (int c2 = 0; c2 < 2; c2++) {
        int c = ch * 2 + c2;
        bf16x8 b0 = *(const bf16x8*)&Wb[((size_t)(0 * 4 + c) * 64 + lane) * 8];
        bf16x8 b1 = *(const bf16x8*)&Wb[((size_t)(1 * 4 + c) * 64 + lane) * 8];
        f32x4 z = {0.f, 0.f, 0.f, 0.f};
        z = __builtin_amdgcn_mfma_f32_16x16x32_bf16(af0, b0, z, 0, 0, 0);
        z = __builtin_amdgcn_mfma_f32_16x16x32_bf16(af1, b1, z, 0, 0, 0);
        acc[c2] = z;
    }
    int lrow = sB * 16 + quad * 4;     // local row 0..31
    int rowbase = blockIdx.x * 32 + lrow;
    float dv2[4];
#pragma unroll
    for (int rr = 0; rr < 4; rr++)
        dv2[rr] = dsh[lrow + rr];
#pragma unroll
    for (int c2 = 0; c2 < 2; c2++) {
        int c = ch * 2 + c2;
#pragma unroll
        for (int rr = 0; rr < 4; rr++) {
            int row = rowbase + rr;
            if (row < n)
                g_out[(size_t)row * 64 + c * 16 + m16] = to_bf16(acc[c2][rr] * dv2[rr]);
        }
    }
}

// --- final aggregation (R12 form + R15 prefetch): 8 lanes/node uint4 ------
__global__ __launch_bounds__(256, 4) void agg_kernel(const unsigned short* __restrict__ g,
                                                     const int* __restrict__ cnt,
                                                     const int* __restrict__ adj,
                                                     const float* __restrict__ bias,
                                                     float* __restrict__ out, int n) {
    int t = threadIdx.x;
    int lg = t & 7;
    int i = blockIdx.x * 32 + (t >> 3);
    if (i >= n) return;
    int deg = cnt[i];
    const int* lst = adj + (size_t)i * CAP;
    const int c8 = lg * 8;
    size_t rowoff = (size_t)i * 64 + c8;
    float a0 = 0.f, a1 = 0.f, a2 = 0.f, a3 = 0.f;
    float a4 = 0.f, a5 = 0.f, a6 = 0.f, a7 = 0.f;
    {   // self loop
        uint4 v = *(const uint4*)&g[(size_t)i * 64 + c8];
        acc_bf16x2(v.x, a0, a1); acc_bf16x2(v.y, a2, a3);
        acc_bf16x2(v.z, a4, a5); acc_bf16x2(v.w, a6, a7);
    }
    int nfull = deg >> 3;
    int4 ja, jb;
    if (nfull > 0) { ja = *(const int4*)&lst[0]; jb = *(const int4*)&lst[4]; }
    for (int b = 0; b < nfull; b++) {
        int4 na = ja, nb = jb;         // prefetch next batch's indices
        if (b + 1 < nfull) {
            na = *(const int4*)&lst[(b + 1) * 8];
            nb = *(const int4*)&lst[(b + 1) * 8 + 4];
        }
        uint4 v0 = *(const uint4*)&g[(size_t)ja.x * 64 + c8];
        uint4 v1 = *(const uint4*)&g[(size_t)ja.y * 64 + c8];
        uint4 v2 = *(const uint4*)&g[(size_t)ja.z * 64 + c8];
        uint4 v3 = *(const uint4*)&g[(size_t)ja.w * 64 + c8];
        uint4 v4 = *(const uint4*)&g[(size_t)jb.x * 64 + c8];
        uint4 v5 = *(const uint4*)&g[(size_t)jb.y * 64 + c8];
        uint4 v6 = *(const uint4*)&g[(size_t)jb.z * 64 + c8];
        uint4 v7 = *(const uint4*)&g[(size_t)jb.w * 64 + c8];
        acc_bf16x2(v0.x, a0, a1); acc_bf16x2(v0.y, a2, a3);
        acc_bf16x2(v0.z, a4, a5); acc_bf16x2(v0.w, a6, a7);
        acc_bf16x2(v1.x, a0, a1); acc_bf16x2(v1.y, a2, a3);
        acc_bf16x2(v1.z, a4, a5); acc_bf16x2(v1.w, a6, a7);
        acc_bf16x2(v2.x, a0, a1); acc_bf16x2(v2.y, a2, a3);
        acc_bf16x2(v2.z, a4, a5); acc_bf16x2(v2.w, a6, a7);
        acc_bf16x2(v3.x, a0, a1); acc_bf16x2(v3.y, a2, a3);
        acc_bf16x2(v3.z, a4, a5); acc_bf16x2(v3.w, a6, a7);
        acc_bf16x2(v4.x, a0, a1); acc_bf16x2(v4.y, a2, a3);
        acc_bf16x2(v4.z, a4, a5); acc_bf16x2(v4.w, a6, a7);
        acc_bf16x2(v5.x, a0, a1); acc_bf16x2(v5.y, a2, a3);
        acc_bf16x2(v5.z, a4, a5); acc_bf16x2(v5.w, a6, a7);
        acc_bf16x2(v6.x, a0, a1); acc_bf16x2(v6.y, a2, a3);
        acc_bf16x2(v6.z, a4, a5); acc_bf16x2(v6.w, a6, a7);
        acc_bf16x2(v7.x, a0, a1); acc_bf16x2(v7.y, a2, a3);
        acc_bf16x2(v7.z, a4, a5); acc_bf16x2(v7.w, a6, a7);
        ja = na; jb = nb;
    }
    int k = nfull * 8;
    if (k + 4 <= deg) {
        int4 j4 = *(const int4*)&lst[k];
        uint4 v0 = *(const uint4*)&g[(size_t)j4.x * 64 + c8];
        uint4 v1 = *(const uint4*)&g[(size_t)j4.y * 64 + c8];
        uint4 v2 = *(const uint4*)&g[(size_t)j4.z * 64 + c8];
        uint4 v3 = *(const uint4*)&g[(size_t)j4.w * 64 + c8];
        acc_bf16x2(v0.x, a0, a1); acc_bf16x2(v0.y, a2, a3);
        acc_bf16x2(v0.z, a4, a5); acc_bf16x2(v0.w, a6, a7);
        acc_bf16x2(v1.x, a0, a1); acc_bf16x2(v1.y, a2, a3);
        acc_bf16x2(v1.z, a4, a5); acc_bf16x2(v1.w, a6, a7);
        acc_bf16x2(v2.x, a0, a1); acc_bf16x2(v2.y, a2, a3);
        acc_bf16x2(v2.z, a4, a5); acc_bf16x2(v2.w, a6, a7);
        acc_bf16x2(v3.x, a0, a1); acc_bf16x2(v3.y, a2, a3);
        acc_bf16x2(v3.z, a4, a5); acc_bf16x2(v3.w, a6, a7);
        k += 4;
    }
    for (; k < deg; k++) {
        uint4 v = *(const uint4*)&g[(size_t)lst[k] * 64 + c8];
        acc_bf16x2(v.x, a0, a1); acc_bf16x2(v.y, a2, a3);
        acc_bf16x2(v.z, a4, a5); acc_bf16x2(v.w, a6, a7);
    }
    float dv = rsqrtf((float)(deg + 1));
    float4 b0 = *(const float4*)&bias[c8];
    float4 b1 = *(const float4*)&bias[c8 + 4];
    float4 o0, o1;
    o0.x = dv * a0 + b0.x; o0.y = dv * a1 + b0.y;
    o0.z = dv * a2 + b0.z; o0.w = dv * a3 + b0.w;
    o1.x = dv * a4 + b1.x; o1.y = dv * a5 + b1.y;
    o1.z = dv * a6 + b1.z; o1.w = dv * a7 + b1.w;
    *(float4*)&out[rowoff] = o0;
    *(float4*)&out[rowoff + 4] = o1;
}

extern "C" void kernel_launch(void* const* d_in, const int* in_sizes, int n_in,
                              void* d_out, int out_size, void* d_ws, size_t ws_size,
                              hipStream_t stream) {
    const float* x  = (const float*)d_in[0];
    const int*   ei = (const int*)d_in[1];
    const float* W1 = (const float*)d_in[2];
    const float* b1 = (const float*)d_in[3];
    const float* W2 = (const float*)d_in[4];
    const float* b2 = (const float*)d_in[5];
    const float* W3 = (const float*)d_in[6];
    const float* b3 = (const float*)d_in[7];
    float* out = (float*)d_out;

    const int N = in_sizes[0] / 64;
    const int E = in_sizes[1] / 2;
    const int* src = ei;
    const int* dst = ei + E;
    const int npc = (N + 7) / 8;
    const int nEdgeChunks = (E + EDGE_CHUNK - 1) / EDGE_CHUNK;

    // workspace layout
    char* p = (char*)d_ws;
    int*            cnt = (int*)p;            p += ((N + 63) / 64) * 64 * 4;
    int*            adj = (int*)p;            p += ((size_t)N + 1) * CAP * 4;
    unsigned short* ga  = (unsigned short*)p; p += (size_t)N * 64 * 2;
    unsigned short* gb  = (unsigned short*)p; p += (size_t)N * 64 * 2;
    float*          h1  = (float*)p;          p += (size_t)N * 64 * 4;

    const int tileBlocks = (N + 63) / 64;   // gemm (64-row MFMA tiles)
    const int halfBlocks = (N + 31) / 32;   // aggemm + final agg (32 nodes)

    // --- bucket adjacency build (ws re-poisoned every call) ---
    hipMemsetAsync(cnt, 0, (size_t)N * 4, stream);
    fill_kernel<<<nEdgeChunks * 8, 256, 0, stream>>>(src, dst, cnt, adj, E, npc);

    // --- layer 1 gemm: ga = dinv ⊙ (x@W1) ---
    gemm_kernel<<<tileBlocks, 256, 0, stream>>>(x, W1, cnt, ga, N);
    // --- fused: h1 = relu(agg(ga))+x ; gb = dinv ⊙ (h1@W2) ---
    aggemm_kernel<1><<<halfBlocks, 256, 0, stream>>>(ga, cnt, adj, b1, x, W2, h1, gb, N);
    // --- fused: h2 = relu(agg(gb))+h1 (kept in-kernel) ; ga = dinv ⊙ (h2@W3) ---
    aggemm_kernel<0><<<halfBlocks, 256, 0, stream>>>(gb, cnt, adj, b2, h1, W3, nullptr, ga, N);
    // --- final: out = agg(ga) + b3 ---
    agg_kernel<<<halfBlocks, 256, 0, stream>>>(ga, cnt, adj, b3, out, N);
}